// Round 1
// baseline (428.796 us; speedup 1.0000x reference)
//
#include <hip/hip_runtime.h>
#include <hip/hip_bf16.h>
#include <stdint.h>

// Problem dims (fixed by reference setup_inputs)
#define Mdim 8192   // B*S = 4*2048
#define Ndim 4096   // OUT
#define Kdim 4096   // IN

#define BM 128
#define BN 128
#define BK 64

typedef int v4i __attribute__((ext_vector_type(4)));

__device__ __forceinline__ void gload_lds16(const void* g, void* l) {
  __builtin_amdgcn_global_load_lds(
      (const __attribute__((address_space(1))) unsigned int*)g,
      (__attribute__((address_space(3))) unsigned int*)l,
      16 /*bytes*/, 0 /*offset*/, 0 /*aux*/);
}

// ---------------------------------------------------------------------------
// Kernel 1: quantize activations. xi = clip(rint((x*input_scale)/act_scale))
// 16 int8 outputs per thread; float4 global loads; matches np.round (rne).
// ---------------------------------------------------------------------------
__global__ void quant_x_kernel(const float* __restrict__ x,
                               const float* __restrict__ in_scale,
                               const float* __restrict__ act_scale_p,
                               int8_t* __restrict__ xq) {
  const float act = *act_scale_p;
  const int64_t tid = (int64_t)blockIdx.x * blockDim.x + threadIdx.x;
  const int64_t base = tid * 16;
  const int k0 = (int)(base & (Kdim - 1));  // Kdim is pow2
  const float4* xv = (const float4*)(x + base);
  const float4* sv = (const float4*)(in_scale + k0);
  alignas(16) int8_t ob[16];
#pragma unroll
  for (int j = 0; j < 4; ++j) {
    float4 xx = xv[j];
    float4 ss = sv[j];
    float r0 = rintf((xx.x * ss.x) / act);
    float r1 = rintf((xx.y * ss.y) / act);
    float r2 = rintf((xx.z * ss.z) / act);
    float r3 = rintf((xx.w * ss.w) / act);
    r0 = fminf(fmaxf(r0, -127.f), 127.f);
    r1 = fminf(fmaxf(r1, -127.f), 127.f);
    r2 = fminf(fmaxf(r2, -127.f), 127.f);
    r3 = fminf(fmaxf(r3, -127.f), 127.f);
    ob[j * 4 + 0] = (int8_t)r0;
    ob[j * 4 + 1] = (int8_t)r1;
    ob[j * 4 + 2] = (int8_t)r2;
    ob[j * 4 + 3] = (int8_t)r3;
  }
  *(v4i*)(xq + base) = *(const v4i*)ob;
}

// ---------------------------------------------------------------------------
// Kernel 2: pack int32 weights (values already in [-127,127]) to int8.
// w is [OUT, IN] = [N, K] row-major -> already K-major (B^T), keep layout.
// ---------------------------------------------------------------------------
__global__ void pack_w_kernel(const int* __restrict__ w, int8_t* __restrict__ wq) {
  const int64_t tid = (int64_t)blockIdx.x * blockDim.x + threadIdx.x;
  const int64_t base = tid * 16;
  const int4* wv = (const int4*)(w + base);
  alignas(16) int8_t ob[16];
#pragma unroll
  for (int j = 0; j < 4; ++j) {
    int4 t = wv[j];
    ob[j * 4 + 0] = (int8_t)t.x;
    ob[j * 4 + 1] = (int8_t)t.y;
    ob[j * 4 + 2] = (int8_t)t.z;
    ob[j * 4 + 3] = (int8_t)t.w;
  }
  *(v4i*)(wq + base) = *(const v4i*)ob;
}

// ---------------------------------------------------------------------------
// Kernel 3: int8 GEMM, m97 structure. C[M,N] = Aq[M,K] . Bq[N,K]^T
// 128x128 tile, BK=64, 4 waves each doing 4x4 grid of mfma_i32_16x16x64_i8.
// global_load_lds width=16 staging (wave-uniform base + lane*16 layout).
// Epilogue: out = acc * (act_scale * w_scale[n]) + bias[n], fp32.
// ---------------------------------------------------------------------------
__global__ __launch_bounds__(256) void gemm_i8_kernel(
    const int8_t* __restrict__ Aq, const int8_t* __restrict__ Bq,
    const float* __restrict__ w_scale, const float* __restrict__ bias,
    const float* __restrict__ act_scale_p, float* __restrict__ out) {
  __shared__ alignas(16) int8_t As[BM * BK];  // 8 KB, [m][k], row stride 64B
  __shared__ alignas(16) int8_t Bs[BN * BK];  // 8 KB, [n][k]

  const int t = threadIdx.x;
  const int n0 = blockIdx.x * BN;
  const int m0 = blockIdx.y * BM;

  // Staging map: thread t loads 16B; tile bytes are [row][k] contiguous.
  // Round 0 covers rows 0..63, round 1 rows 64..127.
  const int srow = t >> 2;        // 0..63
  const int scol = (t & 3) * 16;  // 0/16/32/48
  const int8_t* gA0 = Aq + (int64_t)(m0 + srow) * Kdim + scol;
  const int8_t* gA1 = gA0 + (int64_t)64 * Kdim;
  const int8_t* gB0 = Bq + (int64_t)(n0 + srow) * Kdim + scol;
  const int8_t* gB1 = gB0 + (int64_t)64 * Kdim;
  int8_t* lA0 = As + t * 16;        // == wave base + lane*16 (uniform-base rule)
  int8_t* lA1 = As + 4096 + t * 16;
  int8_t* lB0 = Bs + t * 16;
  int8_t* lB1 = Bs + 4096 + t * 16;

  const int w = t >> 6;          // wave 0..3
  const int l = t & 63;          // lane
  const int wm = (w >> 1) * 64;  // wave's C-block row origin within tile
  const int wn = (w & 1) * 64;   // wave's C-block col origin
  const int lrow = l & 15;       // fragment row (m for A, n for B)
  const int lk = (l >> 4) * 16;  // fragment k-chunk byte offset

  v4i acc[4][4] = {};

  for (int kt = 0; kt < Kdim; kt += BK) {
    gload_lds16(gA0 + kt, lA0);
    gload_lds16(gA1 + kt, lA1);
    gload_lds16(gB0 + kt, lB0);
    gload_lds16(gB1 + kt, lB1);
    __syncthreads();  // compiler drains vmcnt before s_barrier

    v4i af[4], bf[4];
#pragma unroll
    for (int i = 0; i < 4; ++i) {
      af[i] = *(const v4i*)(As + (wm + i * 16 + lrow) * BK + lk);
      bf[i] = *(const v4i*)(Bs + (wn + i * 16 + lrow) * BK + lk);
    }
#pragma unroll
    for (int i = 0; i < 4; ++i) {
#pragma unroll
      for (int j = 0; j < 4; ++j) {
        acc[i][j] = __builtin_amdgcn_mfma_i32_16x16x64_i8(af[i], bf[j], acc[i][j], 0, 0, 0);
      }
    }
    __syncthreads();  // protect LDS before next stage overwrites
  }

  // Epilogue: D mapping col = lane&15, row = (lane>>4)*4 + reg
  const float act = *act_scale_p;
  const int rowbase = (l >> 4) * 4;
#pragma unroll
  for (int j = 0; j < 4; ++j) {
    const int n = n0 + wn + j * 16 + lrow;
    const float sc = act * w_scale[n];
    const float bs = bias[n];
#pragma unroll
    for (int i = 0; i < 4; ++i) {
      const int mb = m0 + wm + i * 16 + rowbase;
#pragma unroll
      for (int r = 0; r < 4; ++r) {
        out[(int64_t)(mb + r) * Ndim + n] = (float)acc[i][j][r] * sc + bs;
      }
    }
  }
}

// ---------------------------------------------------------------------------
extern "C" void kernel_launch(void* const* d_in, const int* in_sizes, int n_in,
                              void* d_out, int out_size, void* d_ws, size_t ws_size,
                              hipStream_t stream) {
  const float* x        = (const float*)d_in[0];
  const float* in_scale = (const float*)d_in[1];
  const float* actp     = (const float*)d_in[2];
  const int*   w_int    = (const int*)d_in[3];
  const float* w_scale  = (const float*)d_in[4];
  const float* bias     = (const float*)d_in[5];
  float* out = (float*)d_out;

  int8_t* Aq = (int8_t*)d_ws;                          // 8192*4096 = 32 MiB
  int8_t* Bq = (int8_t*)d_ws + (size_t)Mdim * Kdim;    // 4096*4096 = 16 MiB

  {
    const int64_t nthreads = (int64_t)Mdim * Kdim / 16;  // 2,097,152
    quant_x_kernel<<<(int)(nthreads / 256), 256, 0, stream>>>(x, in_scale, actp, Aq);
  }
  {
    const int64_t nthreads = (int64_t)Ndim * Kdim / 16;  // 1,048,576
    pack_w_kernel<<<(int)(nthreads / 256), 256, 0, stream>>>(w_int, Bq);
  }
  {
    dim3 grid(Ndim / BN, Mdim / BM);  // (32, 64)
    gemm_i8_kernel<<<grid, 256, 0, stream>>>(Aq, Bq, w_scale, bias, actp, out);
  }
}